// Round 9
// baseline (19.358 us; speedup 1.0000x reference)
//
#include <hip/hip_runtime.h>
#include <hip/hip_bf16.h>

#define VOCAB   32000
#define DIM     5120
#define VDIM    768
#define BATCH   2
#define TLEN    512
#define NTOK    (BATCH * TLEN)       // 1024 tokens
#define TVIS    32
#define NSTATIC (VOCAB + 2)          // 32002
#define NROWS   (BATCH * TVIS)       // 64 possible vision rows
#define NPROJ   (DIM / 16)           // 320 projection blocks

typedef __attribute__((ext_vector_type(8))) short short8_t;
typedef __attribute__((ext_vector_type(4))) float floatx4;

// pack two f32x4 registers into a bf16x8 MFMA fragment
__device__ __forceinline__ short8_t pack8(const floatx4 f0, const floatx4 f1) {
    union { __hip_bfloat16 h[8]; short8_t v; } u;
    u.h[0] = __float2bfloat16(f0.x); u.h[1] = __float2bfloat16(f0.y);
    u.h[2] = __float2bfloat16(f0.z); u.h[3] = __float2bfloat16(f0.w);
    u.h[4] = __float2bfloat16(f1.x); u.h[5] = __float2bfloat16(f1.y);
    u.h[6] = __float2bfloat16(f1.z); u.h[7] = __float2bfloat16(f1.w);
    return u.v;
}
// cached load variant (vf is reused across blocks -> keep in L2)
__device__ __forceinline__ short8_t cvt8(const float* __restrict__ p) {
    return pack8(*reinterpret_cast<const floatx4*>(p),
                 *reinterpret_cast<const floatx4*>(p + 4));
}

// ---------------------------------------------------------------------------
// Single kernel, two roles, one dispatch, no workspace.
//   blocks [0, 320):    proj role. Prefetch this block's fc_w slice; scan
//                       text with int4 loads + register 64-bit row masks +
//                       shfl-OR reduce (ONE barrier, zero atomics); MFMA only
//                       the referenced vision rows; fold the 4-wave K-partial
//                       reduce + bias into the vision-token write.
//   blocks [320, 1344): gather role. out[bt] = static table row, nontemporal,
//                       all 5 loads issued before the 5 stores (MLP).
// ---------------------------------------------------------------------------
__global__ __launch_bounds__(256) void fused_kernel(
    const int*   __restrict__ text,   // [1024]
    const float* __restrict__ vf,     // [64][768]
    const float* __restrict__ fcw,    // [5120][768]
    const float* __restrict__ fcb,    // [5120]
    const float* __restrict__ weight, // [32000][5120]
    const float* __restrict__ fig,    // [2][5120]
    float*       __restrict__ out)    // [1024][5120]
{
    const int tid = threadIdx.x;

    if (blockIdx.x < NPROJ) {
        // ---- projection role ----
        __shared__ float sAcc[4][NROWS][17];       // +1 pad -> 2-way banks (free)
        __shared__ unsigned long long sMask[4];    // per-wave row masks
        __shared__ unsigned char rowList[NROWS];   // compacted slot -> row
        __shared__ unsigned char slotOf[NROWS];    // row -> slot
        __shared__ unsigned char vrow[NTOK];       // token -> vis row (0xFF none)

        const int wave = tid >> 6;
        const int lane = tid & 63;
        const int l15  = lane & 15;
        const int lhi  = lane >> 4;
        const int d0   = blockIdx.x * 16;

        // wave's K range: [wave*192, +192), fragment k-offset lhi*8
        const int kbase = wave * 192 + lhi * 8;
        const float* wp = &fcw[(size_t)(d0 + l15) * VDIM + kbase]; // HBM

        // prefetch the entire fc_w slice FIRST (independent of the scan);
        // the scan + reduce below hide the HBM latency of these 12 loads.
        floatx4 bf[12];
#pragma unroll
        for (int j = 0; j < 6; ++j) {
            const floatx4* p = reinterpret_cast<const floatx4*>(wp + j * 32);
            bf[2 * j]     = __builtin_nontemporal_load(p);
            bf[2 * j + 1] = __builtin_nontemporal_load(p + 1);
        }

        // scan: 4 contiguous tokens per thread via int4, no atomics
        const int4 tv   = reinterpret_cast<const int4*>(text)[tid];
        const int  bofs = (tid >> 7) * TVIS;       // batch offset (t4<512 ? 0 : 32)
        unsigned long long m = 0ull;
        unsigned char c[4];
        const int ids[4] = {tv.x, tv.y, tv.z, tv.w};
#pragma unroll
        for (int j = 0; j < 4; ++j) {
            const int idx = ids[j];
            if (idx >= NSTATIC) {
                int v = idx - NSTATIC;
                if (v > TVIS - 1) v = TVIS - 1;    // clip high (jnp.clip)
                const int r = bofs + v;
                m |= 1ull << r;
                c[j] = (unsigned char)r;
            } else {
                c[j] = 0xFF;
            }
        }
        *reinterpret_cast<uchar4*>(&vrow[tid * 4]) = make_uchar4(c[0], c[1], c[2], c[3]);

        // wave-level OR-reduce of the row mask (6 shuffle steps)
#pragma unroll
        for (int off = 1; off < 64; off <<= 1)
            m |= __shfl_xor(m, off, 64);
        if (lane == 0) sMask[wave] = m;
        __syncthreads();                           // the ONE pre-MFMA barrier

        const unsigned long long m64 = sMask[0] | sMask[1] | sMask[2] | sMask[3];
        const int cnt = (int)__popcll(m64);
        if (cnt == 0) return;                      // no vision tokens at all

        // each wave builds rowList/slotOf redundantly (lane r owns row r);
        // all waves write identical values -> benign, no barrier needed
        {
            const int slot = (int)__popcll(m64 & ((1ull << lane) - 1ull));
            if ((m64 >> lane) & 1ull) {
                rowList[slot] = (unsigned char)lane;
                slotOf[lane]  = (unsigned char)slot;
            }
        }
        const int ngrp = (cnt + 15) >> 4;          // 16-row MFMA groups (<=4)

        int myrow[4];
#pragma unroll
        for (int g = 0; g < 4; ++g) {
            const int s = g * 16 + l15;
            myrow[g] = rowList[s < cnt ? s : 0];
        }

        floatx4 acc[4];
#pragma unroll
        for (int g = 0; g < 4; ++g) acc[g] = floatx4{0.f, 0.f, 0.f, 0.f};

#pragma unroll
        for (int j = 0; j < 6; ++j) {              // 6 chunks of k-32
            const short8_t b = pack8(bf[2 * j], bf[2 * j + 1]);
#pragma unroll
            for (int g = 0; g < 4; ++g) {          // block-uniform guard
                if (g < ngrp) {
                    const short8_t a = cvt8(&vf[(size_t)myrow[g] * VDIM + kbase + j * 32]);
                    acc[g] = __builtin_amdgcn_mfma_f32_16x16x32_bf16(a, b, acc[g], 0, 0, 0);
                }
            }
        }

        // C/D layout: col = lane&15 (-> d), row = (lane>>4)*4 + reg (-> slot)
#pragma unroll
        for (int g = 0; g < 4; ++g)
            if (g < ngrp)
#pragma unroll
                for (int rr = 0; rr < 4; ++rr)
                    sAcc[wave][g * 16 + lhi * 4 + rr][l15] = acc[g][rr];
        __syncthreads();

        // write our 16 columns for each vision token, folding the 4-wave
        // K-partial reduce + bias into the write (16 threads per token)
        const int   grp  = tid >> 4;
        const int   dcol = tid & 15;
        const float bias = fcb[d0 + dcol];
        for (int t = grp; t < NTOK; t += 16) {
            const unsigned char rv = vrow[t];      // broadcast within group
            if (rv == 0xFF) continue;
            const int s = slotOf[rv];
            const float v = sAcc[0][s][dcol] + sAcc[1][s][dcol] +
                            sAcc[2][s][dcol] + sAcc[3][s][dcol] + bias;
            out[(size_t)t * DIM + d0 + dcol] = v;
        }
    } else {
        // ---- static-token gather role ----
        const int bt  = blockIdx.x - NPROJ;
        const int idx = text[bt];
        if (idx >= NSTATIC) return;                // vision token: proj role owns it

        int r = idx < 0 ? 0 : idx;                 // clip low (matches jnp.clip)
        const float* src = (r < VOCAB) ? &weight[(size_t)r * DIM]
                                       : &fig[(size_t)(r - VOCAB) * DIM];
        const floatx4* s4 = reinterpret_cast<const floatx4*>(src);
        floatx4*       d4 = reinterpret_cast<floatx4*>(&out[(size_t)bt * DIM]);

        // DIM/4 = 1280 = 5 * 256: fully unrolled, all loads before stores
        floatx4 v0 = __builtin_nontemporal_load(&s4[tid]);
        floatx4 v1 = __builtin_nontemporal_load(&s4[tid + 256]);
        floatx4 v2 = __builtin_nontemporal_load(&s4[tid + 512]);
        floatx4 v3 = __builtin_nontemporal_load(&s4[tid + 768]);
        floatx4 v4 = __builtin_nontemporal_load(&s4[tid + 1024]);
        __builtin_nontemporal_store(v0, &d4[tid]);
        __builtin_nontemporal_store(v1, &d4[tid + 256]);
        __builtin_nontemporal_store(v2, &d4[tid + 512]);
        __builtin_nontemporal_store(v3, &d4[tid + 768]);
        __builtin_nontemporal_store(v4, &d4[tid + 1024]);
    }
}

extern "C" void kernel_launch(void* const* d_in, const int* in_sizes, int n_in,
                              void* d_out, int out_size, void* d_ws, size_t ws_size,
                              hipStream_t stream) {
    (void)in_sizes; (void)n_in; (void)out_size; (void)d_ws; (void)ws_size;
    const int*   text = (const int*)  d_in[0];  // (B,T) int32
    const float* vf   = (const float*)d_in[1];  // (B,TV,VD)
    const float* w    = (const float*)d_in[2];  // (V,D)
    const float* fig  = (const float*)d_in[3];  // (2,D)
    const float* fcw  = (const float*)d_in[4];  // (D,VD)
    const float* fcb  = (const float*)d_in[5];  // (D,)
    float* out = (float*)d_out;                 // (B,T,D) f32

    fused_kernel<<<NPROJ + NTOK, 256, 0, stream>>>(
        text, vf, fcw, fcb, w, fig, out);
}

// Round 10
// 16.013 us; speedup vs baseline: 1.2089x; 1.2089x over previous
//
#include <hip/hip_runtime.h>
#include <hip/hip_bf16.h>

#define VOCAB   32000
#define DIM     5120
#define VDIM    768
#define BATCH   2
#define TLEN    512
#define NTOK    (BATCH * TLEN)       // 1024 tokens
#define TVIS    32
#define NSTATIC (VOCAB + 2)          // 32002
#define NROWS   (BATCH * TVIS)       // 64 possible vision rows
#define NPROJ   (DIM / 16)           // 320 projection blocks

typedef __attribute__((ext_vector_type(8))) short short8_t;
typedef __attribute__((ext_vector_type(4))) float floatx4;

// pack two f32x4 registers into a bf16x8 MFMA fragment
__device__ __forceinline__ short8_t pack8(const floatx4 f0, const floatx4 f1) {
    union { __hip_bfloat16 h[8]; short8_t v; } u;
    u.h[0] = __float2bfloat16(f0.x); u.h[1] = __float2bfloat16(f0.y);
    u.h[2] = __float2bfloat16(f0.z); u.h[3] = __float2bfloat16(f0.w);
    u.h[4] = __float2bfloat16(f1.x); u.h[5] = __float2bfloat16(f1.y);
    u.h[6] = __float2bfloat16(f1.z); u.h[7] = __float2bfloat16(f1.w);
    return u.v;
}
// cached load variant (vf is reused across blocks -> keep in L2)
__device__ __forceinline__ short8_t cvt8(const float* __restrict__ p) {
    return pack8(*reinterpret_cast<const floatx4*>(p),
                 *reinterpret_cast<const floatx4*>(p + 4));
}

// ---------------------------------------------------------------------------
// Single kernel, two roles, one dispatch, no workspace.  (Round-8 structure:
// best measured 16.1 us. Round 9's heavier scan regressed — the fused
// kernel's VGPR budget is shared, and extra scan registers taxed the
// 1024 gather blocks' occupancy. Keep the scan cheap.)
//   blocks [0, 320):    proj role. Prefetch this block's fc_w slice (hides
//                       under the text scan), compact the referenced vision
//                       rows wave-parallel (ballot/popc), MFMA only those
//                       rows, fold the 4-wave K-partial reduce + bias into
//                       the vision-token write.
//   blocks [320, 1344): gather role. out[bt] = static table row, nontemporal,
//                       all 5 loads issued before the 5 stores (MLP).
// ---------------------------------------------------------------------------
__global__ __launch_bounds__(256) void fused_kernel(
    const int*   __restrict__ text,   // [1024]
    const float* __restrict__ vf,     // [64][768]
    const float* __restrict__ fcw,    // [5120][768]
    const float* __restrict__ fcb,    // [5120]
    const float* __restrict__ weight, // [32000][5120]
    const float* __restrict__ fig,    // [2][5120]
    float*       __restrict__ out)    // [1024][5120]
{
    const int tid = threadIdx.x;

    if (blockIdx.x < NPROJ) {
        // ---- projection role ----
        __shared__ float sAcc[4][NROWS][17];      // +1 pad -> 2-way banks (free)
        __shared__ unsigned needMask[2];          // bitmap of needed rows
        __shared__ unsigned char rowList[NROWS];  // compacted slot -> row
        __shared__ unsigned char slotOf[NROWS];   // row -> slot
        __shared__ int visTok[NTOK];              // (t<<6)|r per vision token
        __shared__ int cntSh, nvSh;

        const int wave = tid >> 6;
        const int lane = tid & 63;
        const int l15  = lane & 15;
        const int lhi  = lane >> 4;
        const int d0   = blockIdx.x * 16;

        // wave's K range: [wave*192, +192), fragment k-offset lhi*8
        const int kbase = wave * 192 + lhi * 8;
        const float* wrow = &fcw[(size_t)(d0 + l15) * VDIM + kbase]; // HBM

        // prefetch the entire fc_w slice FIRST (independent of the scan);
        // the scan + barriers below hide the HBM latency of these 12 loads.
        floatx4 bf[12];
#pragma unroll
        for (int j = 0; j < 6; ++j) {
            const floatx4* p = reinterpret_cast<const floatx4*>(wrow + j * 32);
            bf[2 * j]     = __builtin_nontemporal_load(p);
            bf[2 * j + 1] = __builtin_nontemporal_load(p + 1);
        }

        if (tid < 2) needMask[tid] = 0u;
        if (tid == 0) nvSh = 0;
        __syncthreads();

        // scan token ids: mark needed rows, append vision-token list
        for (int t = tid; t < NTOK; t += 256) {
            const int idx = text[t];
            if (idx >= NSTATIC) {
                int vr = idx - NSTATIC;
                if (vr > TVIS - 1) vr = TVIS - 1;     // clip high (jnp.clip)
                const int r = (t >> 9) * TVIS + vr;   // b*32 + vr
                atomicOr(&needMask[r >> 5], 1u << (r & 31));
                visTok[atomicAdd(&nvSh, 1)] = (t << 6) | r;
            }
        }
        __syncthreads();

        // wave-parallel compaction (wave 0): lane r owns row r
        if (tid < 64) {
            const unsigned long long m64 =
                ((unsigned long long)needMask[1] << 32) | needMask[0];
            const unsigned long long below = (tid == 0)
                ? 0ull : (m64 & ((1ull << tid) - 1ull));
            const int slot = (int)__popcll(below);
            if ((m64 >> tid) & 1ull) {
                rowList[slot] = (unsigned char)tid;
                slotOf[tid]   = (unsigned char)slot;
            }
            if (tid == 0) cntSh = (int)__popcll(m64);
        }
        __syncthreads();
        const int cnt = cntSh;
        if (cnt == 0) return;                     // no vision tokens at all

        const int ngrp = (cnt + 15) >> 4;         // 16-row MFMA groups (<=4)

        int myrow[4];
#pragma unroll
        for (int g = 0; g < 4; ++g) {
            const int s = g * 16 + l15;
            myrow[g] = rowList[s < cnt ? s : 0];
        }

        floatx4 acc[4];
#pragma unroll
        for (int g = 0; g < 4; ++g) acc[g] = floatx4{0.f, 0.f, 0.f, 0.f};

#pragma unroll
        for (int j = 0; j < 6; ++j) {             // 6 chunks of k-32
            const short8_t b = pack8(bf[2 * j], bf[2 * j + 1]);
#pragma unroll
            for (int g = 0; g < 4; ++g) {         // block-uniform guard
                if (g < ngrp) {
                    const short8_t a = cvt8(&vf[(size_t)myrow[g] * VDIM + kbase + j * 32]);
                    acc[g] = __builtin_amdgcn_mfma_f32_16x16x32_bf16(a, b, acc[g], 0, 0, 0);
                }
            }
        }

        // C/D layout: col = lane&15 (-> d), row = (lane>>4)*4 + reg (-> slot)
#pragma unroll
        for (int g = 0; g < 4; ++g)
            if (g < ngrp)
#pragma unroll
                for (int rr = 0; rr < 4; ++rr)
                    sAcc[wave][g * 16 + lhi * 4 + rr][l15] = acc[g][rr];
        __syncthreads();

        // write our 16 columns for each vision token, folding the 4-wave
        // K-partial reduce + bias into the write (no separate pass/barrier)
        const int nv = nvSh;
        const int dcol = tid & 15;
        const float bias = fcb[d0 + dcol];
        for (int e = tid >> 4; e < nv; e += 16) {
            const int pk = visTok[e];
            const int t  = pk >> 6;
            const int s  = slotOf[pk & 63];
            const float v = sAcc[0][s][dcol] + sAcc[1][s][dcol] +
                            sAcc[2][s][dcol] + sAcc[3][s][dcol] + bias;
            out[(size_t)t * DIM + d0 + dcol] = v;
        }
    } else {
        // ---- static-token gather role ----
        const int bt  = blockIdx.x - NPROJ;
        const int idx = text[bt];
        if (idx >= NSTATIC) return;               // vision token: proj role owns it

        int r = idx < 0 ? 0 : idx;                // clip low (matches jnp.clip)
        const float* src = (r < VOCAB) ? &weight[(size_t)r * DIM]
                                       : &fig[(size_t)(r - VOCAB) * DIM];
        const floatx4* s4 = reinterpret_cast<const floatx4*>(src);
        floatx4*       d4 = reinterpret_cast<floatx4*>(&out[(size_t)bt * DIM]);

        // DIM/4 = 1280 = 5 * 256: fully unrolled, all loads before stores
        floatx4 v0 = __builtin_nontemporal_load(&s4[tid]);
        floatx4 v1 = __builtin_nontemporal_load(&s4[tid + 256]);
        floatx4 v2 = __builtin_nontemporal_load(&s4[tid + 512]);
        floatx4 v3 = __builtin_nontemporal_load(&s4[tid + 768]);
        floatx4 v4 = __builtin_nontemporal_load(&s4[tid + 1024]);
        __builtin_nontemporal_store(v0, &d4[tid]);
        __builtin_nontemporal_store(v1, &d4[tid + 256]);
        __builtin_nontemporal_store(v2, &d4[tid + 512]);
        __builtin_nontemporal_store(v3, &d4[tid + 768]);
        __builtin_nontemporal_store(v4, &d4[tid + 1024]);
    }
}

extern "C" void kernel_launch(void* const* d_in, const int* in_sizes, int n_in,
                              void* d_out, int out_size, void* d_ws, size_t ws_size,
                              hipStream_t stream) {
    (void)in_sizes; (void)n_in; (void)out_size; (void)d_ws; (void)ws_size;
    const int*   text = (const int*)  d_in[0];  // (B,T) int32
    const float* vf   = (const float*)d_in[1];  // (B,TV,VD)
    const float* w    = (const float*)d_in[2];  // (V,D)
    const float* fig  = (const float*)d_in[3];  // (2,D)
    const float* fcw  = (const float*)d_in[4];  // (D,VD)
    const float* fcb  = (const float*)d_in[5];  // (D,)
    float* out = (float*)d_out;                 // (B,T,D) f32

    fused_kernel<<<NPROJ + NTOK, 256, 0, stream>>>(
        text, vf, fcw, fcb, w, fig, out);
}